// Round 3
// baseline (2165.725 us; speedup 1.0000x reference)
//
#include <hip/hip_runtime.h>

// SurfaceTransolver round 3: store-w pipeline (path A) with round-2 fallback (path B).
//
// Path A (needs ~416 MB ws):
//   pass1A: block=(head,chunk), 128-tok tiles, x global->regs, 3-product logits,
//           softmax -> w; w -> LDS transpose -> global [n][512] hi/lo planes;
//           fx (1-product) + pooling MFMA -> per-block partials.
//   pass3A: 32-tok tiles, w streamed global->MFMA A-frags (no logits recompute);
//           stage1 (w x oslT) -> ox LDS; stage2 (ox x WprojT) -> out. LDS 34KB.
// Path B: round-2 kernels verbatim (w recomputed in pass3).

#define HID 256
#define NH  8
#define DH  32
#define NS  64
#define NQ  512
#define MT  32                 // tokens per tile (pass3 / path B)
#define PSTRIDE 16896          // path B partials stride
#define PSTR_A  2560           // path A: 64*32 pool + 8*64 norm

typedef short bf16x8 __attribute__((ext_vector_type(8)));
typedef float f32x4 __attribute__((ext_vector_type(4)));

#define MFMA(a,b,c) __builtin_amdgcn_mfma_f32_16x16x32_bf16((a),(b),(c),0,0,0)

__device__ __forceinline__ f32x4 zero4() { f32x4 z; z[0]=0.f; z[1]=0.f; z[2]=0.f; z[3]=0.f; return z; }

__device__ __forceinline__ ushort bf_rne(float f) {
  unsigned u = __float_as_uint(f);
  return (ushort)((u + 0x7FFFu + ((u >> 16) & 1u)) >> 16);
}
__device__ __forceinline__ void split2(float f, ushort& h, ushort& l) {
  h = bf_rne(f);
  float fh = __uint_as_float(((unsigned)h) << 16);
  l = bf_rne(f - fh);
}

// ---------------- K0a ----------------
__global__ __launch_bounds__(256) void k_build_wlog(
    const float* __restrict__ Wx, const float* __restrict__ bx,
    const float* __restrict__ Wsl, const float* __restrict__ bsl,
    const float* __restrict__ temp,
    ushort* __restrict__ wlh, ushort* __restrict__ wll, float* __restrict__ blog)
{
  const int q = blockIdx.x, k = threadIdx.x;
  const int h = q >> 6, s = q & 63;
  const float it = 1.0f / temp[h];
  float acc = 0.f;
#pragma unroll
  for (int c = 0; c < DH; ++c)
    acc = fmaf(Wx[k * HID + h * DH + c], Wsl[c * NS + s], acc);
  acc *= it;
  ushort hh, ll; split2(acc, hh, ll);
  wlh[q * HID + k] = hh; wll[q * HID + k] = ll;
  if (k == 0) {
    float b = bsl[s];
    for (int c = 0; c < DH; ++c) b = fmaf(bx[h * DH + c], Wsl[c * NS + s], b);
    blog[q] = b * it;
  }
}

// ---------------- K0b ----------------
__global__ __launch_bounds__(256) void k_build_wfxt(
    const float* __restrict__ Wfx, ushort* __restrict__ wfxth)
{
  const int c = blockIdx.x, k = threadIdx.x;
  wfxth[c * HID + k] = bf_rne(Wfx[k * HID + c]);
}

// ---------------- K0c ----------------
__global__ __launch_bounds__(256) void k_build_wprojt(
    const float* __restrict__ Wproj, ushort* __restrict__ wpth, ushort* __restrict__ wptl)
{
  const int hc = blockIdx.x, j = threadIdx.x;
  ushort hh, ll; split2(Wproj[hc * HID + j], hh, ll);
  wpth[j * HID + hc] = hh; wptl[j * HID + hc] = ll;
}

// =======================================================================
// PATH A
// =======================================================================

// Pass 1A: block = (head h = blockIdx&7, chunk = blockIdx>>3); 128-token tiles.
__global__ __launch_bounds__(512, 4) void k_pass1A(
    const float* __restrict__ x, const float* __restrict__ mask,
    const ushort* __restrict__ wlogh, const ushort* __restrict__ wlogl,
    const float* __restrict__ blog,
    const ushort* __restrict__ wfxth, const float* __restrict__ bfx,
    ushort* __restrict__ whg, ushort* __restrict__ wlg,
    float* __restrict__ partials, int Ntok, int ntiles, int nchunks)
{
  __shared__ ushort wTh[64][136];   // w^T hi: [q_local][tok], pad 8
  __shared__ ushort wTl[64][136];
  __shared__ ushort fxT[32][136];   // fx^T: [c_local][tok]
  __shared__ float msk[128];

  const int t = threadIdx.x;
  const int wv = t >> 6, lane = t & 63, lr = lane & 15, lg = lane >> 4;
  const int h = blockIdx.x & 7, chunk = blockIdx.x >> 3;

  float blg[4], bfr[2];
#pragma unroll
  for (int cf = 0; cf < 4; ++cf) blg[cf] = blog[h * 64 + cf * 16 + lr];
#pragma unroll
  for (int cf = 0; cf < 2; ++cf) bfr[cf] = bfx[h * 32 + cf * 16 + lr];

  const int sf = wv >> 1, cp = wv & 1;   // pooling fragment owned by this wave
  f32x4 pool = zero4();
  float nacc[4] = {0.f, 0.f, 0.f, 0.f};

  for (int tile = chunk; tile < ntiles; tile += nchunks) {
    const int n0 = tile * 128;
    __syncthreads();                       // LDS reuse guard
    if (t < 128) msk[t] = (n0 + t < Ntok) ? mask[n0 + t] : 0.f;
    __syncthreads();

    // ---- logits (3-product) + fx (1-product), x global->regs ----
    f32x4 acc[4];
    f32x4 fxa[2];
#pragma unroll
    for (int cf = 0; cf < 4; ++cf) acc[cf] = zero4();
    fxa[0] = zero4(); fxa[1] = zero4();
    const int row = n0 + wv * 16 + lr;
    const bool valid = row < Ntok;
    const float* xrow = x + (size_t)row * HID;

#pragma unroll
    for (int kk = 0; kk < 8; ++kk) {
      float v[8];
      if (valid) {
        const float4* xp = (const float4*)(xrow + kk * 32 + lg * 8);
        float4 f0 = xp[0], f1 = xp[1];
        v[0]=f0.x; v[1]=f0.y; v[2]=f0.z; v[3]=f0.w;
        v[4]=f1.x; v[5]=f1.y; v[6]=f1.z; v[7]=f1.w;
      } else {
#pragma unroll
        for (int i = 0; i < 8; ++i) v[i] = 0.f;
      }
      union { ushort u[8]; bf16x8 v8; } AH, AL;
#pragma unroll
      for (int i = 0; i < 8; ++i) split2(v[i], AH.u[i], AL.u[i]);
#pragma unroll
      for (int cf = 0; cf < 4; ++cf) {
        const size_t bo = (size_t)(h * 64 + cf * 16 + lr) * HID + kk * 32 + lg * 8;
        bf16x8 bh = *reinterpret_cast<const bf16x8*>(wlogh + bo);
        bf16x8 bl = *reinterpret_cast<const bf16x8*>(wlogl + bo);
        acc[cf] = MFMA(AH.v8, bh, acc[cf]);
        acc[cf] = MFMA(AL.v8, bh, acc[cf]);
        acc[cf] = MFMA(AH.v8, bl, acc[cf]);
      }
#pragma unroll
      for (int cf = 0; cf < 2; ++cf) {
        const size_t bo = (size_t)(h * 32 + cf * 16 + lr) * HID + kk * 32 + lg * 8;
        bf16x8 bf = *reinterpret_cast<const bf16x8*>(wfxth + bo);
        fxa[cf] = MFMA(AH.v8, bf, fxa[cf]);
      }
    }

    // ---- softmax per token row (q spread over cf regs + lr lanes) ----
#pragma unroll
    for (int r = 0; r < 4; ++r) {
      float mx = -1e30f;
#pragma unroll
      for (int cf = 0; cf < 4; ++cf) { float vv = acc[cf][r] + blg[cf]; acc[cf][r] = vv; mx = fmaxf(mx, vv); }
      mx = fmaxf(mx, __shfl_xor(mx, 1)); mx = fmaxf(mx, __shfl_xor(mx, 2));
      mx = fmaxf(mx, __shfl_xor(mx, 4)); mx = fmaxf(mx, __shfl_xor(mx, 8));
      float sm = 0.f;
#pragma unroll
      for (int cf = 0; cf < 4; ++cf) { float e = __expf(acc[cf][r] - mx); acc[cf][r] = e; sm += e; }
      sm += __shfl_xor(sm, 1); sm += __shfl_xor(sm, 2); sm += __shfl_xor(sm, 4); sm += __shfl_xor(sm, 8);
      const float sc = msk[wv * 16 + lg * 4 + r] / sm;
#pragma unroll
      for (int cf = 0; cf < 4; ++cf) acc[cf][r] *= sc;
    }

    // ---- w -> LDS (hi/lo) + norm partial; fx -> LDS ----
#pragma unroll
    for (int cf = 0; cf < 4; ++cf)
#pragma unroll
      for (int r = 0; r < 4; ++r) {
        const int tok = wv * 16 + lg * 4 + r;
        ushort hh, ll; split2(acc[cf][r], hh, ll);
        wTh[cf * 16 + lr][tok] = hh;
        wTl[cf * 16 + lr][tok] = ll;
        nacc[cf] += acc[cf][r];
      }
#pragma unroll
    for (int cf = 0; cf < 2; ++cf)
#pragma unroll
      for (int r = 0; r < 4; ++r)
        fxT[cf * 16 + lr][wv * 16 + lg * 4 + r] = bf_rne(fxa[cf][r] + bfr[cf]);
    __syncthreads();

    // ---- pooling MFMA: num[s][c] += w^T * fx^T  (K=128 toks, 1 frag/wave) ----
#pragma unroll
    for (int ks = 0; ks < 4; ++ks) {
      bf16x8 a = *reinterpret_cast<const bf16x8*>(&wTh[sf * 16 + lr][ks * 32 + lg * 8]);
      bf16x8 b = *reinterpret_cast<const bf16x8*>(&fxT[cp * 16 + lr][ks * 32 + lg * 8]);
      pool = MFMA(a, b, pool);
    }

    // ---- transposed w write to global [n][512] hi/lo planes ----
    {
      const int tok = t >> 2, qg = (t & 3) * 16;
      const int n = n0 + tok;
      if (n < Ntok) {
        union { ushort u[16]; bf16x8 v8[2]; } H, L;
#pragma unroll
        for (int i = 0; i < 16; ++i) { H.u[i] = wTh[qg + i][tok]; L.u[i] = wTl[qg + i][tok]; }
        ushort* dh = whg + (size_t)n * NQ + h * 64 + qg;
        ushort* dl = wlg + (size_t)n * NQ + h * 64 + qg;
        *reinterpret_cast<bf16x8*>(dh)     = H.v8[0];
        *reinterpret_cast<bf16x8*>(dh + 8) = H.v8[1];
        *reinterpret_cast<bf16x8*>(dl)     = L.v8[0];
        *reinterpret_cast<bf16x8*>(dl + 8) = L.v8[1];
      }
    }
  }

  // ---- epilogue partials ----
  float* pb = partials + (size_t)blockIdx.x * PSTR_A;
#pragma unroll
  for (int r = 0; r < 4; ++r)
    pb[(sf * 16 + lg * 4 + r) * 32 + cp * 16 + lr] = pool[r];
#pragma unroll
  for (int cf = 0; cf < 4; ++cf) {
    float v = nacc[cf];
    v += __shfl_xor(v, 16); v += __shfl_xor(v, 32);
    if (lg == 0) pb[2048 + wv * 64 + cf * 16 + lr] = v;
  }
}

__global__ __launch_bounds__(512) void k_reduce_normA(
    const float* __restrict__ P, float* __restrict__ normbuf, int nchunks)
{
  const int q = threadIdx.x;             // 0..511
  const int h = q >> 6, ql = q & 63;
  float s = 0.f;
  for (int c = 0; c < nchunks; ++c) {
    const float* pb = P + (size_t)(c * 8 + h) * PSTR_A + 2048;
#pragma unroll
    for (int wv = 0; wv < 8; ++wv) s += pb[wv * 64 + ql];
  }
  normbuf[q] = s;
}

__global__ __launch_bounds__(256) void k_reduce_numA(
    const float* __restrict__ P, const float* __restrict__ normbuf,
    float* __restrict__ st, int nchunks)
{
  const int idx = blockIdx.x * 256 + threadIdx.x;    // q*32 + c, 16384
  const int q = idx >> 5, h = q >> 6;
  float a = 0.f;
  for (int c = 0; c < nchunks; ++c)
    a += P[(size_t)(c * 8 + h) * PSTR_A + (idx & 2047)];
  st[idx] = a / (normbuf[q] + 1e-5f);
}

// Pass 3A: stream w from global, stage1 + stage2 only.
__global__ __launch_bounds__(512, 4) void k_pass3A(
    const float* __restrict__ mask,
    const ushort* __restrict__ whg, const ushort* __restrict__ wlg,
    const ushort* __restrict__ oslth, const ushort* __restrict__ osltl,
    const ushort* __restrict__ wpth, const ushort* __restrict__ wptl,
    const float* __restrict__ bproj,
    float* __restrict__ out, int Ntok, int ntiles, int ngrid)
{
  __shared__ ushort oxh[MT * 264];
  __shared__ ushort oxl[MT * 264];
  __shared__ float msk[MT];

  const int t = threadIdx.x;
  const int w = t >> 6, lane = t & 63, lr = lane & 15, lg = lane >> 4;
  float bprr[2];
#pragma unroll
  for (int cf = 0; cf < 2; ++cf) bprr[cf] = bproj[w * 32 + cf * 16 + lr];

  const bf16x8 zv = {0,0,0,0,0,0,0,0};

  for (int tile = blockIdx.x; tile < ntiles; tile += ngrid) {
    const int n0 = tile * MT;
    __syncthreads();
    if (t < MT) msk[t] = (n0 + t < Ntok) ? mask[n0 + t] : 0.f;

    // ---- stage 1: ox[tok][hc] = sum_s w[tok][h*64+s] * osl[h][s][c], 3-product ----
    f32x4 s1[2][2];
    s1[0][0] = zero4(); s1[0][1] = zero4(); s1[1][0] = zero4(); s1[1][1] = zero4();
#pragma unroll
    for (int kk = 0; kk < 2; ++kk)
#pragma unroll
      for (int rf = 0; rf < 2; ++rf) {
        const int rowi = n0 + rf * 16 + lr;
        bf16x8 ah = zv, al = zv;
        if (rowi < Ntok) {
          const size_t o = (size_t)rowi * NQ + w * 64 + kk * 32 + lg * 8;
          ah = *reinterpret_cast<const bf16x8*>(whg + o);
          al = *reinterpret_cast<const bf16x8*>(wlg + o);
        }
#pragma unroll
        for (int cf = 0; cf < 2; ++cf) {
          const size_t bo = (size_t)(w * 32 + cf * 16 + lr) * NS + kk * 32 + lg * 8;
          bf16x8 bh = *reinterpret_cast<const bf16x8*>(oslth + bo);
          bf16x8 bl = *reinterpret_cast<const bf16x8*>(osltl + bo);
          s1[rf][cf] = MFMA(ah, bh, s1[rf][cf]);
          s1[rf][cf] = MFMA(al, bh, s1[rf][cf]);
          s1[rf][cf] = MFMA(ah, bl, s1[rf][cf]);
        }
      }
#pragma unroll
    for (int rf = 0; rf < 2; ++rf)
#pragma unroll
      for (int cf = 0; cf < 2; ++cf)
#pragma unroll
        for (int r = 0; r < 4; ++r) {
          const int tok = rf * 16 + lg * 4 + r;
          const int hc = w * 32 + cf * 16 + lr;
          ushort hh, ll; split2(s1[rf][cf][r], hh, ll);
          oxh[tok * 264 + hc] = hh; oxl[tok * 264 + hc] = ll;
        }
    __syncthreads();

    // ---- stage 2: out = mask*(mask*(ox @ WprojT) + bproj), 3-product ----
    f32x4 s2[2][2];
    s2[0][0] = zero4(); s2[0][1] = zero4(); s2[1][0] = zero4(); s2[1][1] = zero4();
#pragma unroll
    for (int kk = 0; kk < 8; ++kk)
#pragma unroll
      for (int rf = 0; rf < 2; ++rf) {
        bf16x8 a_h = *reinterpret_cast<const bf16x8*>(&oxh[(rf * 16 + lr) * 264 + kk * 32 + lg * 8]);
        bf16x8 a_l = *reinterpret_cast<const bf16x8*>(&oxl[(rf * 16 + lr) * 264 + kk * 32 + lg * 8]);
#pragma unroll
        for (int cf = 0; cf < 2; ++cf) {
          const size_t bo = (size_t)(w * 32 + cf * 16 + lr) * HID + kk * 32 + lg * 8;
          bf16x8 bh = *reinterpret_cast<const bf16x8*>(wpth + bo);
          bf16x8 bl = *reinterpret_cast<const bf16x8*>(wptl + bo);
          s2[rf][cf] = MFMA(a_h, bh, s2[rf][cf]);
          s2[rf][cf] = MFMA(a_l, bh, s2[rf][cf]);
          s2[rf][cf] = MFMA(a_h, bl, s2[rf][cf]);
        }
      }
#pragma unroll
    for (int rf = 0; rf < 2; ++rf)
#pragma unroll
      for (int cf = 0; cf < 2; ++cf)
#pragma unroll
        for (int r = 0; r < 4; ++r) {
          const int tok = rf * 16 + lg * 4 + r;
          const int n = n0 + tok;
          if (n < Ntok) {
            const int j = w * 32 + cf * 16 + lr;
            const float mk = msk[tok];
            out[(size_t)n * HID + j] = mk * (mk * s2[rf][cf][r] + bprr[cf]);
          }
        }
  }
}

// =======================================================================
// PATH B (round-2 kernels, fallback when ws is too small)
// =======================================================================

__global__ __launch_bounds__(512, 4) void k_pass1(
    const float* __restrict__ x, const float* __restrict__ mask,
    const ushort* __restrict__ wlogh, const float* __restrict__ blog,
    const ushort* __restrict__ wfxth, const float* __restrict__ bfx,
    float* __restrict__ partials, int Ntok, int ntiles, int ngrid)
{
  __shared__ ushort xh[MT * 264];
  __shared__ ushort wt[NQ * 40];
  __shared__ ushort fxt[HID * 40];
  __shared__ float msk[MT];

  const int t = threadIdx.x;
  const int w = t >> 6, lane = t & 63, lr = lane & 15, lg = lane >> 4;

  float blogr[4], bfxr[2];
#pragma unroll
  for (int cf = 0; cf < 4; ++cf) blogr[cf] = blog[w * 64 + cf * 16 + lr];
#pragma unroll
  for (int cf = 0; cf < 2; ++cf) bfxr[cf] = bfx[w * 32 + cf * 16 + lr];

  f32x4 pool[4][2];
#pragma unroll
  for (int sf = 0; sf < 4; ++sf) { pool[sf][0] = zero4(); pool[sf][1] = zero4(); }
  float nacc[4] = {0.f, 0.f, 0.f, 0.f};

  for (int tile = blockIdx.x; tile < ntiles; tile += ngrid) {
    const int n0 = tile * MT;
    __syncthreads();
    {
      const int tok = t >> 4, sg = (t & 15) * 16;
      float v[16];
      if (n0 + tok < Ntok) {
        const float4* src = (const float4*)(x + (size_t)(n0 + tok) * HID + sg);
#pragma unroll
        for (int i = 0; i < 4; ++i) { float4 f = src[i]; v[i*4]=f.x; v[i*4+1]=f.y; v[i*4+2]=f.z; v[i*4+3]=f.w; }
      } else {
#pragma unroll
        for (int i = 0; i < 16; ++i) v[i] = 0.f;
      }
      union { ushort u[16]; bf16x8 v8[2]; } H;
#pragma unroll
      for (int i = 0; i < 16; ++i) H.u[i] = bf_rne(v[i]);
      *reinterpret_cast<bf16x8*>(&xh[tok * 264 + sg]) = H.v8[0];
      *reinterpret_cast<bf16x8*>(&xh[tok * 264 + sg + 8]) = H.v8[1];
      if (t < MT) msk[t] = (n0 + t < Ntok) ? mask[n0 + t] : 0.f;
    }
    __syncthreads();

    f32x4 acc[2][4];
#pragma unroll
    for (int rf = 0; rf < 2; ++rf)
#pragma unroll
      for (int cf = 0; cf < 4; ++cf) acc[rf][cf] = zero4();
#pragma unroll
    for (int kk = 0; kk < HID; kk += 32) {
      bf16x8 ah0 = *reinterpret_cast<const bf16x8*>(&xh[lr * 264 + kk + lg * 8]);
      bf16x8 ah1 = *reinterpret_cast<const bf16x8*>(&xh[(16 + lr) * 264 + kk + lg * 8]);
#pragma unroll
      for (int cf = 0; cf < 4; ++cf) {
        bf16x8 bh = *reinterpret_cast<const bf16x8*>(wlogh + (size_t)(w * 64 + cf * 16 + lr) * HID + kk + lg * 8);
        acc[0][cf] = MFMA(ah0, bh, acc[0][cf]);
        acc[1][cf] = MFMA(ah1, bh, acc[1][cf]);
      }
    }
#pragma unroll
    for (int rf = 0; rf < 2; ++rf)
#pragma unroll
      for (int r = 0; r < 4; ++r) {
        float mx = -1e30f;
#pragma unroll
        for (int cf = 0; cf < 4; ++cf) { float vv = acc[rf][cf][r] + blogr[cf]; acc[rf][cf][r] = vv; mx = fmaxf(mx, vv); }
        mx = fmaxf(mx, __shfl_xor(mx, 1)); mx = fmaxf(mx, __shfl_xor(mx, 2));
        mx = fmaxf(mx, __shfl_xor(mx, 4)); mx = fmaxf(mx, __shfl_xor(mx, 8));
        float sm = 0.f;
#pragma unroll
        for (int cf = 0; cf < 4; ++cf) { float e = __expf(acc[rf][cf][r] - mx); acc[rf][cf][r] = e; sm += e; }
        sm += __shfl_xor(sm, 1); sm += __shfl_xor(sm, 2); sm += __shfl_xor(sm, 4); sm += __shfl_xor(sm, 8);
        const float sc = msk[rf * 16 + lg * 4 + r] / sm;
#pragma unroll
        for (int cf = 0; cf < 4; ++cf) acc[rf][cf][r] *= sc;
      }
#pragma unroll
    for (int rf = 0; rf < 2; ++rf)
#pragma unroll
      for (int cf = 0; cf < 4; ++cf)
#pragma unroll
        for (int r = 0; r < 4; ++r) {
          const int tok = rf * 16 + lg * 4 + r;
          const int q = w * 64 + cf * 16 + lr;
          wt[q * 40 + tok] = bf_rne(acc[rf][cf][r]);
          nacc[cf] += acc[rf][cf][r];
        }
    f32x4 fa[2][2];
    fa[0][0] = zero4(); fa[0][1] = zero4(); fa[1][0] = zero4(); fa[1][1] = zero4();
#pragma unroll
    for (int kk = 0; kk < HID; kk += 32) {
      bf16x8 ah0 = *reinterpret_cast<const bf16x8*>(&xh[lr * 264 + kk + lg * 8]);
      bf16x8 ah1 = *reinterpret_cast<const bf16x8*>(&xh[(16 + lr) * 264 + kk + lg * 8]);
#pragma unroll
      for (int cf = 0; cf < 2; ++cf) {
        bf16x8 bh = *reinterpret_cast<const bf16x8*>(wfxth + (size_t)(w * 32 + cf * 16 + lr) * HID + kk + lg * 8);
        fa[0][cf] = MFMA(ah0, bh, fa[0][cf]);
        fa[1][cf] = MFMA(ah1, bh, fa[1][cf]);
      }
    }
#pragma unroll
    for (int rf = 0; rf < 2; ++rf)
#pragma unroll
      for (int cf = 0; cf < 2; ++cf)
#pragma unroll
        for (int r = 0; r < 4; ++r) {
          const int tok = rf * 16 + lg * 4 + r;
          const int hc = w * 32 + cf * 16 + lr;
          fxt[hc * 40 + tok] = bf_rne(fa[rf][cf][r] + bfxr[cf]);
        }
    __syncthreads();
    {
      bf16x8 b0 = *reinterpret_cast<const bf16x8*>(&fxt[(w * 32 + lr) * 40 + lg * 8]);
      bf16x8 b1 = *reinterpret_cast<const bf16x8*>(&fxt[(w * 32 + 16 + lr) * 40 + lg * 8]);
#pragma unroll
      for (int sf = 0; sf < 4; ++sf) {
        bf16x8 a = *reinterpret_cast<const bf16x8*>(&wt[(w * 64 + sf * 16 + lr) * 40 + lg * 8]);
        pool[sf][0] = MFMA(a, b0, pool[sf][0]);
        pool[sf][1] = MFMA(a, b1, pool[sf][1]);
      }
    }
  }
  float* pb = partials + (size_t)blockIdx.x * PSTRIDE;
#pragma unroll
  for (int sf = 0; sf < 4; ++sf)
#pragma unroll
    for (int cp = 0; cp < 2; ++cp)
#pragma unroll
      for (int r = 0; r < 4; ++r) {
        const int s = sf * 16 + lg * 4 + r;
        const int hcl = cp * 16 + lr;
        pb[w * 2048 + s * 32 + hcl] = pool[sf][cp][r];
      }
#pragma unroll
  for (int cf = 0; cf < 4; ++cf) {
    float v = nacc[cf];
    v += __shfl_xor(v, 16); v += __shfl_xor(v, 32);
    if (lg == 0) pb[16384 + w * 64 + cf * 16 + lr] = v;
  }
}

__global__ __launch_bounds__(256) void k_reduce_norm(
    const float* __restrict__ partials, float* __restrict__ normbuf, int nb)
{
  const int p = blockIdx.x * 256 + threadIdx.x;
  float s = 0.f;
  for (int b = 0; b < nb; ++b) s += partials[(size_t)b * PSTRIDE + 16384 + p];
  normbuf[p] = s;
}

__global__ __launch_bounds__(256) void k_reduce_num(
    const float* __restrict__ partials, const float* __restrict__ normbuf,
    float* __restrict__ st, int nb)
{
  const int pidx = blockIdx.x * 256 + threadIdx.x;
  float acc = 0.f;
  for (int b = 0; b < nb; ++b) acc += partials[(size_t)b * PSTRIDE + pidx];
  st[pidx] = acc / (normbuf[pidx >> 5] + 1e-5f);
}

// ---------------- SDPA (shared by both paths) ----------------
__global__ __launch_bounds__(64) void k_sdpa(
    const float* __restrict__ st, const float* __restrict__ Wqkv,
    ushort* __restrict__ oslth, ushort* __restrict__ osltl)
{
  __shared__ float stt[NS][DH + 1];
  __shared__ float kt[NS][DH + 1];
  __shared__ float vt[NS][DH + 1];
  const int h = blockIdx.x, sr = threadIdx.x;
  for (int i = sr; i < NS * DH; i += 64) stt[i >> 5][i & 31] = st[(size_t)h * NS * DH + i];
  __syncthreads();
  float qr[DH];
#pragma unroll
  for (int c = 0; c < DH; ++c) {
    float aq = 0.f, ak = 0.f, av = 0.f;
#pragma unroll
    for (int i = 0; i < DH; ++i) {
      const float sv = stt[sr][i];
      aq = fmaf(sv, Wqkv[i * 96 + c], aq);
      ak = fmaf(sv, Wqkv[i * 96 + 32 + c], ak);
      av = fmaf(sv, Wqkv[i * 96 + 64 + c], av);
    }
    qr[c] = aq; kt[sr][c] = ak; vt[sr][c] = av;
  }
  __syncthreads();
  float sc[NS];
  float m = -1e30f;
  const float scale = 0.17677669529663687f;
#pragma unroll
  for (int tt = 0; tt < NS; ++tt) {
    float a = 0.f;
#pragma unroll
    for (int c = 0; c < DH; ++c) a = fmaf(qr[c], kt[tt][c], a);
    a *= scale; sc[tt] = a; m = fmaxf(m, a);
  }
  float sum = 0.f;
#pragma unroll
  for (int tt = 0; tt < NS; ++tt) { const float e = __expf(sc[tt] - m); sc[tt] = e; sum += e; }
  const float inv = 1.f / sum;
#pragma unroll
  for (int c = 0; c < DH; ++c) {
    float o = 0.f;
#pragma unroll
    for (int tt = 0; tt < NS; ++tt) o = fmaf(sc[tt], vt[tt][c], o);
    o *= inv;
    ushort hh, ll; split2(o, hh, ll);
    oslth[(h * DH + c) * NS + sr] = hh;
    osltl[(h * DH + c) * NS + sr] = ll;
  }
}

// ---------------- Pass 3 (path B) ----------------
__global__ __launch_bounds__(512, 2) void k_pass3(
    const float* __restrict__ x, const float* __restrict__ mask,
    const ushort* __restrict__ wlogh, const ushort* __restrict__ wlogl,
    const float* __restrict__ blog,
    const ushort* __restrict__ oslth, const ushort* __restrict__ osltl,
    const ushort* __restrict__ wpth, const ushort* __restrict__ wptl,
    const float* __restrict__ bproj,
    float* __restrict__ out, int Ntok, int ntiles, int ngrid)
{
  __shared__ ushort xh[MT * 264];
  __shared__ ushort xl[MT * 264];
  __shared__ ushort wh[MT * 520];
  __shared__ ushort wl[MT * 520];
  __shared__ float msk[MT];

  const int t = threadIdx.x;
  const int w = t >> 6, lane = t & 63, lr = lane & 15, lg = lane >> 4;

  float blogr[4], bprr[2];
#pragma unroll
  for (int cf = 0; cf < 4; ++cf) blogr[cf] = blog[w * 64 + cf * 16 + lr];
#pragma unroll
  for (int cf = 0; cf < 2; ++cf) bprr[cf] = bproj[w * 32 + cf * 16 + lr];

  for (int tile = blockIdx.x; tile < ntiles; tile += ngrid) {
    const int n0 = tile * MT;
    __syncthreads();
    {
      const int tok = t >> 4, sg = (t & 15) * 16;
      float v[16];
      if (n0 + tok < Ntok) {
        const float4* src = (const float4*)(x + (size_t)(n0 + tok) * HID + sg);
#pragma unroll
        for (int i = 0; i < 4; ++i) { float4 f = src[i]; v[i*4]=f.x; v[i*4+1]=f.y; v[i*4+2]=f.z; v[i*4+3]=f.w; }
      } else {
#pragma unroll
        for (int i = 0; i < 16; ++i) v[i] = 0.f;
      }
      union { ushort u[16]; bf16x8 v8[2]; } H, L;
#pragma unroll
      for (int i = 0; i < 16; ++i) split2(v[i], H.u[i], L.u[i]);
      *reinterpret_cast<bf16x8*>(&xh[tok * 264 + sg]) = H.v8[0];
      *reinterpret_cast<bf16x8*>(&xh[tok * 264 + sg + 8]) = H.v8[1];
      *reinterpret_cast<bf16x8*>(&xl[tok * 264 + sg]) = L.v8[0];
      *reinterpret_cast<bf16x8*>(&xl[tok * 264 + sg + 8]) = L.v8[1];
      if (t < MT) msk[t] = (n0 + t < Ntok) ? mask[n0 + t] : 0.f;
    }
    __syncthreads();

    f32x4 acc[2][4];
#pragma unroll
    for (int rf = 0; rf < 2; ++rf)
#pragma unroll
      for (int cf = 0; cf < 4; ++cf) acc[rf][cf] = zero4();
#pragma unroll
    for (int kk = 0; kk < HID; kk += 32) {
      bf16x8 ah0 = *reinterpret_cast<const bf16x8*>(&xh[lr * 264 + kk + lg * 8]);
      bf16x8 ah1 = *reinterpret_cast<const bf16x8*>(&xh[(16 + lr) * 264 + kk + lg * 8]);
      bf16x8 al0 = *reinterpret_cast<const bf16x8*>(&xl[lr * 264 + kk + lg * 8]);
      bf16x8 al1 = *reinterpret_cast<const bf16x8*>(&xl[(16 + lr) * 264 + kk + lg * 8]);
#pragma unroll
      for (int cf = 0; cf < 4; ++cf) {
        const size_t bo = (size_t)(w * 64 + cf * 16 + lr) * HID + kk + lg * 8;
        bf16x8 bh = *reinterpret_cast<const bf16x8*>(wlogh + bo);
        bf16x8 bl = *reinterpret_cast<const bf16x8*>(wlogl + bo);
        acc[0][cf] = MFMA(ah0, bh, acc[0][cf]);
        acc[0][cf] = MFMA(al0, bh, acc[0][cf]);
        acc[0][cf] = MFMA(ah0, bl, acc[0][cf]);
        acc[1][cf] = MFMA(ah1, bh, acc[1][cf]);
        acc[1][cf] = MFMA(al1, bh, acc[1][cf]);
        acc[1][cf] = MFMA(ah1, bl, acc[1][cf]);
      }
    }
#pragma unroll
    for (int rf = 0; rf < 2; ++rf)
#pragma unroll
      for (int r = 0; r < 4; ++r) {
        float mx = -1e30f;
#pragma unroll
        for (int cf = 0; cf < 4; ++cf) { float vv = acc[rf][cf][r] + blogr[cf]; acc[rf][cf][r] = vv; mx = fmaxf(mx, vv); }
        mx = fmaxf(mx, __shfl_xor(mx, 1)); mx = fmaxf(mx, __shfl_xor(mx, 2));
        mx = fmaxf(mx, __shfl_xor(mx, 4)); mx = fmaxf(mx, __shfl_xor(mx, 8));
        float sm = 0.f;
#pragma unroll
        for (int cf = 0; cf < 4; ++cf) { float e = __expf(acc[rf][cf][r] - mx); acc[rf][cf][r] = e; sm += e; }
        sm += __shfl_xor(sm, 1); sm += __shfl_xor(sm, 2); sm += __shfl_xor(sm, 4); sm += __shfl_xor(sm, 8);
        const float sc = msk[rf * 16 + lg * 4 + r] / sm;
#pragma unroll
        for (int cf = 0; cf < 4; ++cf) acc[rf][cf][r] *= sc;
      }
#pragma unroll
    for (int rf = 0; rf < 2; ++rf)
#pragma unroll
      for (int cf = 0; cf < 4; ++cf)
#pragma unroll
        for (int r = 0; r < 4; ++r) {
          const int tok = rf * 16 + lg * 4 + r;
          const int q = w * 64 + cf * 16 + lr;
          ushort hh, ll; split2(acc[rf][cf][r], hh, ll);
          wh[tok * 520 + q] = hh; wl[tok * 520 + q] = ll;
        }
    __syncthreads();

    f32x4 s1[2][2];
    s1[0][0] = zero4(); s1[0][1] = zero4(); s1[1][0] = zero4(); s1[1][1] = zero4();
#pragma unroll
    for (int kk = 0; kk < NS; kk += 32) {
#pragma unroll
      for (int rf = 0; rf < 2; ++rf) {
        bf16x8 a_h = *reinterpret_cast<const bf16x8*>(&wh[(rf * 16 + lr) * 520 + w * 64 + kk + lg * 8]);
        bf16x8 a_l = *reinterpret_cast<const bf16x8*>(&wl[(rf * 16 + lr) * 520 + w * 64 + kk + lg * 8]);
#pragma unroll
        for (int cf = 0; cf < 2; ++cf) {
          const size_t bo = (size_t)(w * 32 + cf * 16 + lr) * NS + kk + lg * 8;
          bf16x8 bh = *reinterpret_cast<const bf16x8*>(oslth + bo);
          bf16x8 bl = *reinterpret_cast<const bf16x8*>(osltl + bo);
          s1[rf][cf] = MFMA(a_h, bh, s1[rf][cf]);
          s1[rf][cf] = MFMA(a_l, bh, s1[rf][cf]);
          s1[rf][cf] = MFMA(a_h, bl, s1[rf][cf]);
        }
      }
    }
#pragma unroll
    for (int rf = 0; rf < 2; ++rf)
#pragma unroll
      for (int cf = 0; cf < 2; ++cf)
#pragma unroll
        for (int r = 0; r < 4; ++r) {
          const int tok = rf * 16 + lg * 4 + r;
          const int hc = w * 32 + cf * 16 + lr;
          ushort hh, ll; split2(s1[rf][cf][r], hh, ll);
          xh[tok * 264 + hc] = hh; xl[tok * 264 + hc] = ll;
        }
    __syncthreads();

    f32x4 s2[2][2];
    s2[0][0] = zero4(); s2[0][1] = zero4(); s2[1][0] = zero4(); s2[1][1] = zero4();
#pragma unroll
    for (int kk = 0; kk < HID; kk += 32) {
#pragma unroll
      for (int rf = 0; rf < 2; ++rf) {
        bf16x8 a_h = *reinterpret_cast<const bf16x8*>(&xh[(rf * 16 + lr) * 264 + kk + lg * 8]);
        bf16x8 a_l = *reinterpret_cast<const bf16x8*>(&xl[(rf * 16 + lr) * 264 + kk + lg * 8]);
#pragma unroll
        for (int cf = 0; cf < 2; ++cf) {
          const size_t bo = (size_t)(w * 32 + cf * 16 + lr) * HID + kk + lg * 8;
          bf16x8 bh = *reinterpret_cast<const bf16x8*>(wpth + bo);
          bf16x8 bl = *reinterpret_cast<const bf16x8*>(wptl + bo);
          s2[rf][cf] = MFMA(a_h, bh, s2[rf][cf]);
          s2[rf][cf] = MFMA(a_l, bh, s2[rf][cf]);
          s2[rf][cf] = MFMA(a_h, bl, s2[rf][cf]);
        }
      }
    }
#pragma unroll
    for (int rf = 0; rf < 2; ++rf)
#pragma unroll
      for (int cf = 0; cf < 2; ++cf)
#pragma unroll
        for (int r = 0; r < 4; ++r) {
          const int tok = rf * 16 + lg * 4 + r;
          const int n = n0 + tok;
          if (n < Ntok) {
            const int j = w * 32 + cf * 16 + lr;
            const float mk = msk[tok];
            out[(size_t)n * HID + j] = mk * (mk * s2[rf][cf][r] + bprr[cf]);
          }
        }
  }
}

extern "C" void kernel_launch(void* const* d_in, const int* in_sizes, int n_in,
                              void* d_out, int out_size, void* d_ws, size_t ws_size,
                              hipStream_t stream)
{
  const float* x     = (const float*)d_in[0];
  const float* mask  = (const float*)d_in[1];
  const float* Wfx   = (const float*)d_in[2];
  const float* bfx   = (const float*)d_in[3];
  const float* Wx    = (const float*)d_in[4];
  const float* bx    = (const float*)d_in[5];
  const float* Wsl   = (const float*)d_in[6];
  const float* bsl   = (const float*)d_in[7];
  const float* Wqkv  = (const float*)d_in[8];
  const float* Wproj = (const float*)d_in[9];
  const float* bproj = (const float*)d_in[10];
  const float* temp  = (const float*)d_in[11];
  float* out = (float*)d_out;

  const int Ntok = in_sizes[0] / HID;             // 200000

  // ---- shared prefix allocations ----
  char* ws = (char*)d_ws;
  size_t off = 0;
  ushort* wlogh = (ushort*)(ws + off); off += (size_t)NQ * HID * 2;
  ushort* wlogl = (ushort*)(ws + off); off += (size_t)NQ * HID * 2;
  float*  blog  = (float*)(ws + off);  off += NQ * 4;
  ushort* wfxth = (ushort*)(ws + off); off += (size_t)HID * HID * 2;
  ushort* wpth  = (ushort*)(ws + off); off += (size_t)HID * HID * 2;
  ushort* wptl  = (ushort*)(ws + off); off += (size_t)HID * HID * 2;
  ushort* oslth = (ushort*)(ws + off); off += (size_t)NQ * DH * 2;
  ushort* osltl = (ushort*)(ws + off); off += (size_t)NQ * DH * 2;
  float*  stb   = (float*)(ws + off);  off += (size_t)NQ * DH * 4;
  float*  normb = (float*)(ws + off);  off += NQ * 4;

  const int NCHUNK = 64;                          // path-A chunks per head
  const size_t needA = off + (size_t)NCHUNK * 8 * PSTR_A * 4
                     + 2 * (size_t)Ntok * NQ * 2 + 256;

  k_build_wlog<<<dim3(NQ), dim3(256), 0, stream>>>(Wx, bx, Wsl, bsl, temp, wlogh, wlogl, blog);
  k_build_wfxt<<<dim3(HID), dim3(256), 0, stream>>>(Wfx, wfxth);
  k_build_wprojt<<<dim3(HID), dim3(256), 0, stream>>>(Wproj, wpth, wptl);

  if (ws_size >= needA) {
    // ---------------- PATH A ----------------
    float*  partialsA = (float*)(ws + off); off += (size_t)NCHUNK * 8 * PSTR_A * 4;
    ushort* whg = (ushort*)(ws + off); off += (size_t)Ntok * NQ * 2;
    ushort* wlg = (ushort*)(ws + off); off += (size_t)Ntok * NQ * 2;

    const int ntiles128 = (Ntok + 127) / 128;
    const int ntiles32  = (Ntok + MT - 1) / MT;

    k_pass1A<<<dim3(8 * NCHUNK), dim3(512), 0, stream>>>(
        x, mask, wlogh, wlogl, blog, wfxth, bfx, whg, wlg,
        partialsA, Ntok, ntiles128, NCHUNK);
    k_reduce_normA<<<dim3(1), dim3(512), 0, stream>>>(partialsA, normb, NCHUNK);
    k_reduce_numA<<<dim3(64), dim3(256), 0, stream>>>(partialsA, normb, stb, NCHUNK);
    k_sdpa<<<dim3(NH), dim3(64), 0, stream>>>(stb, Wqkv, oslth, osltl);
    k_pass3A<<<dim3(1024), dim3(512), 0, stream>>>(
        mask, whg, wlg, oslth, osltl, wpth, wptl, bproj, out, Ntok, ntiles32, 1024);
  } else {
    // ---------------- PATH B (round-2 fallback) ----------------
    const int ntiles = (Ntok + MT - 1) / MT;
    int nb1 = 512;
    while (nb1 > 1 && off + (size_t)nb1 * PSTRIDE * 4 > ws_size) nb1 >>= 1;
    float* partials = (float*)(ws + off);

    k_pass1<<<dim3(nb1), dim3(512), 0, stream>>>(x, mask, wlogh, blog, wfxth, bfx,
                                                 partials, Ntok, ntiles, nb1);
    k_reduce_norm<<<dim3(2), dim3(256), 0, stream>>>(partials, normb, nb1);
    k_reduce_num<<<dim3(64), dim3(256), 0, stream>>>(partials, normb, stb, nb1);
    k_sdpa<<<dim3(NH), dim3(64), 0, stream>>>(stb, Wqkv, oslth, osltl);
    k_pass3<<<dim3(256), dim3(512), 0, stream>>>(x, mask, wlogh, wlogl, blog,
                                                 oslth, osltl, wpth, wptl, bproj,
                                                 out, Ntok, ntiles, 256);
  }
}